// Round 15
// baseline (153.711 us; speedup 1.0000x reference)
//
#include <hip/hip_runtime.h>
#include <float.h>

// ROI adaptive max-pool 7x7. features [512,64,64] fp32, 1024 ROIs.
// == R14 champion (29.4us) + ONE delta: persistent-block pool with per-XCD
// dynamic work-stealing. Block durations vary ~20x (ROI area 4..81); static
// 2-round scheduling leaves the store pipe idle during straggler tails.
// Now each WAVE steals one (ROI x 64ch) unit via lane-0 atomicAdd on a
// per-XCD counter (readfirstlane -> unit id is SGPR, rois[] stays s_load).
// Per-XCD counters preserve R9's bc<->XCD L2 keying. Wave-inner code is
// byte-identical to R14 (templated WL/HL branch-free row DAG, LDS-transpose
// epilogue, non-temporal stores).
constexpr int CC = 512, HH = 64, WW = 64, HW = HH * WW;
constexpr size_t FT_BYTES = (size_t)CC * HW * sizeof(float);
#define NEG (-FLT_MAX)
typedef float f4 __attribute__((ext_vector_type(4)));

// ---------- phase 1: [C][HW] -> [HW][C], XCD-keyed by channel chunk ----------
__global__ __launch_bounds__(256) void transpose_kernel(
    const float* __restrict__ f, float* __restrict__ ft)
{
    __shared__ float tile[64][65];
    int bc = blockIdx.x & 7;             // channel slice -> XCD bc
    int bs = blockIdx.x >> 3;            // hw tile (4096/64)
    int tx = threadIdx.x & 63, ty0 = threadIdx.x >> 6;
#pragma unroll
    for (int k = 0; k < 16; ++k) {
        int c = k * 4 + ty0;
        tile[c][tx] = __builtin_nontemporal_load(
            &f[(size_t)(bc * 64 + c) * HW + bs * 64 + tx]);          // read-once
    }
    __syncthreads();
#pragma unroll
    for (int k = 0; k < 16; ++k) {
        int s = k * 4 + ty0;
        ft[(size_t)(bs * 64 + s) * CC + bc * 64 + tx] = tile[tx][s]; // cached: pool re-reads
    }
}

// ---------- fully-specialized row phase: all windows compile-time ----------
template <int WL, int HL>
__device__ __forceinline__ void pool_rows(
    const float* __restrict__ fbase,     // ft + c0 + lane
    int y1, int x1,
    float (&acc)[7][7])
{
#pragma unroll
    for (int t = 0; t < HL; ++t) {       // FULL unroll: branch-free DAG
        const float* rowp = fbase + (size_t)(y1 + t) * (WW * CC);
        float v[WL];
#pragma unroll
        for (int k = 0; k < WL; ++k)     // exactly WL coalesced loads
            v[k] = rowp[(x1 + k) * CC];
        float m[7];
#pragma unroll
        for (int j = 0; j < 7; ++j) {    // constant w-windows: pure fmax tree
            const int s = (j * WL) / 7;
            const int e = ((j + 1) * WL + 6) / 7;
            float a = v[s];
#pragma unroll
            for (int k = s + 1; k < e; ++k) a = fmaxf(a, v[k]);
            m[j] = a;
        }
#pragma unroll
        for (int i = 0; i < 7; ++i) {    // constant h-windows: folds away
            if (t >= (i * HL) / 7 && t < ((i + 1) * HL + 6) / 7) {
#pragma unroll
                for (int j = 0; j < 7; ++j)
                    acc[i][j] = fmaxf(acc[i][j], m[j]);
            }
        }
    }
}

// ---------- phase 2: persistent pool, per-XCD work-stealing ----------
__global__ __launch_bounds__(256) void pool_kernel(
    const float* __restrict__ ft,        // [H][W][C]
    const int4*  __restrict__ rois,      // [R] (x1,y1,x2,y2) image px
    float* __restrict__ out,             // [R,C,7,7]
    unsigned int* __restrict__ cnt,      // [8] per-XCD unit counters (zeroed)
    int nunits)                          // units per XCD == R (one per ROI)
{
    __shared__ __align__(16) float lds[4][32 * 49];
    int wslot = threadIdx.x >> 6;
    int lane  = threadIdx.x & 63;
    int bc = __builtin_amdgcn_readfirstlane(blockIdx.x) & 7;  // XCD key
    int c0 = bc << 6;                    // this XCD's 64-channel chunk
    float* L = lds[wslot];

    for (;;) {
        // wave steals one ROI unit (lane 0 atomic, broadcast to SGPR)
        unsigned int t0 = 0;
        if (lane == 0) t0 = atomicAdd(&cnt[bc], 1u);
        int r = __builtin_amdgcn_readfirstlane((int)t0);
        if (r >= nunits) break;

        int4 roi = rois[r];              // uniform -> s_load
        // (px * 1/16.f) truncated == px >> 4 for px in [0,1024): exact fp32.
        int x1 = roi.x >> 4, y1 = roi.y >> 4, x2 = roi.z >> 4, y2 = roi.w >> 4;
        int hl = y2 - y1 + 1, wl = x2 - x1 + 1;   // 2..9 each
        wl = min(max(wl, 2), 9);         // safety clamp (construction: [2,9])
        hl = min(max(hl, 2), 9);

        float acc[7][7];
#pragma unroll
        for (int i = 0; i < 7; ++i)
#pragma unroll
            for (int j = 0; j < 7; ++j) acc[i][j] = NEG;

        const float* fbase = ft + c0 + lane;
#define POOL_CASE(W, H) \
        case ((W - 2) * 8 + (H - 2)): pool_rows<W, H>(fbase, y1, x1, acc); break;
#define POOL_CASES_W(W) \
        POOL_CASE(W, 2) POOL_CASE(W, 3) POOL_CASE(W, 4) POOL_CASE(W, 5) \
        POOL_CASE(W, 6) POOL_CASE(W, 7) POOL_CASE(W, 8) POOL_CASE(W, 9)
        switch ((wl - 2) * 8 + (hl - 2)) {   // wave-uniform dispatch
            POOL_CASES_W(2) POOL_CASES_W(3) POOL_CASES_W(4) POOL_CASES_W(5)
            POOL_CASES_W(6) POOL_CASES_W(7) POOL_CASES_W(8) POOL_CASES_W(9)
            default: break;                  // unreachable
        }
#undef POOL_CASES_W
#undef POOL_CASE

        // Store: transpose [64ch][49] -> [c][bin] via LDS, 2 rounds of 32ch.
        float* ob = out + ((size_t)r * CC + c0) * 49;
#pragma unroll
        for (int round = 0; round < 2; ++round) {
            if ((lane >> 5) == round) {
                float* p = L + (lane & 31) * 49;  // stride 49: conflict-free
#pragma unroll
                for (int i = 0; i < 7; ++i)
#pragma unroll
                    for (int j = 0; j < 7; ++j) p[i * 7 + j] = acc[i][j];
            }
            asm volatile("s_waitcnt lgkmcnt(0)" ::: "memory");
            float* og = ob + round * 1568;        // 1568 floats contiguous
#pragma unroll
            for (int s = 0; s < 6; ++s) {         // 6 x (64 lanes x dwordx4)
                int idx = s * 64 + lane;
                __builtin_nontemporal_store(*(const f4*)(L + idx * 4),
                                            (f4*)(og + idx * 4));
            }
            if (lane < 8) {                       // 392 = 6*64 + 8 tail
                int idx = 384 + lane;
                __builtin_nontemporal_store(*(const f4*)(L + idx * 4),
                                            (f4*)(og + idx * 4));
            }
            // LDS reads done before re-deposit (next round / next unit)
            asm volatile("s_waitcnt lgkmcnt(0)" ::: "memory");
        }
    }
}

// ---------- fallback (R4, proven): used only if ws too small ----------
__global__ __launch_bounds__(256) void roi_pool_direct(
    const float* __restrict__ features, const int4* __restrict__ rois,
    float* __restrict__ out, int ngroups)
{
    int wid = __builtin_amdgcn_readfirstlane(
        blockIdx.x * (blockDim.x >> 6) + (threadIdx.x >> 6));
    if (wid >= ngroups) return;
    int lane = threadIdx.x & 63;
    if (lane >= 49) return;
    int r = wid >> 4, c0 = (wid & 15) * 32;
    int4 roi = rois[r];
    int x1 = roi.x >> 4, y1 = roi.y >> 4, x2 = roi.z >> 4, y2 = roi.w >> 4;
    int h_len = y2 - y1 + 1, w_len = x2 - x1 + 1;
    int oh = lane / 7, ow = lane - oh * 7;
    int hs = y1 + (oh * h_len) / 7, he = y1 + ((oh + 1) * h_len + 6) / 7;
    int ws = x1 + (ow * w_len) / 7, we = x1 + ((ow + 1) * w_len + 6) / 7;
    int wlst = we - 1;
    int wa = ws, wb = min(ws + 1, wlst), wc = min(ws + 2, wlst);
    bool need1 = hs + 1 < he, need2 = hs + 2 < he;
    int o0 = (hs * WW + wa) * 4, o0b = (hs * WW + wb) * 4, o0c = (hs * WW + wc) * 4;
    const char* fb = (const char*)features + (size_t)c0 * (HW * 4);
    float* ob = out + ((size_t)r * CC + c0) * 49 + lane;
#pragma unroll 4
    for (int j = 0; j < 32; ++j) {
        float a = fmaxf(fmaxf(*(const float*)(fb + o0),
                              *(const float*)(fb + o0b)),
                        *(const float*)(fb + o0c));
        if (need1) {
            a = fmaxf(a, fmaxf(fmaxf(*(const float*)(fb + o0 + WW * 4),
                                     *(const float*)(fb + o0b + WW * 4)),
                               *(const float*)(fb + o0c + WW * 4)));
        }
        if (need2) {
            a = fmaxf(a, fmaxf(fmaxf(*(const float*)(fb + o0 + 2 * WW * 4),
                                     *(const float*)(fb + o0b + 2 * WW * 4)),
                               *(const float*)(fb + o0c + 2 * WW * 4)));
        }
        *ob = a;
        fb += HW * 4;
        ob += 49;
    }
}

extern "C" void kernel_launch(void* const* d_in, const int* in_sizes, int n_in,
                              void* d_out, int out_size, void* d_ws, size_t ws_size,
                              hipStream_t stream) {
    const float* features = (const float*)d_in[0];   // [1,512,64,64] fp32
    const int4*  rois     = (const int4*)d_in[1];    // [R,4] int32
    float* out = (float*)d_out;
    int R = out_size / (CC * 49);                    // 1024

    if (ws_size >= FT_BYTES + 8 * sizeof(unsigned int)) {
        float* ft = (float*)d_ws;                    // [HW][C], 8 MB
        unsigned int* cnt = (unsigned int*)((char*)d_ws + FT_BYTES);
        transpose_kernel<<<512, 256, 0, stream>>>(features, ft);
        hipMemsetAsync(cnt, 0, 8 * sizeof(unsigned int), stream);
        pool_kernel<<<1024, 256, 0, stream>>>(ft, rois, out, cnt, R);
    } else {
        int ngroups = R * 16;
        roi_pool_direct<<<(ngroups + 3) / 4, 256, 0, stream>>>(features, rois, out, ngroups);
    }
}

// Round 16
// 42.189 us; speedup vs baseline: 3.6434x; 3.6434x over previous
//
#include <hip/hip_runtime.h>
#include <float.h>

// ROI adaptive max-pool 7x7. features [512,64,64] fp32, 1024 ROIs.
// == R14 champion + per-XCD dynamic work-stealing, CONTENTION-FIXED:
// R15 put all 8 counters in ONE 32B cache line -> every device-scope
// atomicAdd from 8 XCDs serialized at a single coherence point (~12K x
// ~30cy = the 143us observed). Now each counter is PADDED TO ITS OWN
// 128B LINE: the 8 atomic streams serialize independently (~1536 ops
// each, parallel across L2 banks), overlapped with compute.
// Each WAVE steals one (ROI x 64ch) unit (lane-0 atomicAdd, readfirstlane
// -> unit id SGPR, rois[] stays s_load). Per-XCD counters preserve R9's
// bc<->XCD L2 keying. Wave-inner code byte-identical to R14 (templated
// WL/HL branch-free row DAG, LDS-transpose epilogue, nt stores).
constexpr int CC = 512, HH = 64, WW = 64, HW = HH * WW;
constexpr size_t FT_BYTES = (size_t)CC * HW * sizeof(float);
constexpr int CNT_STRIDE = 32;           // uints: 128 B between counters
#define NEG (-FLT_MAX)
typedef float f4 __attribute__((ext_vector_type(4)));

// ---------- phase 1: [C][HW] -> [HW][C], XCD-keyed by channel chunk ----------
__global__ __launch_bounds__(256) void transpose_kernel(
    const float* __restrict__ f, float* __restrict__ ft)
{
    __shared__ float tile[64][65];
    int bc = blockIdx.x & 7;             // channel slice -> XCD bc
    int bs = blockIdx.x >> 3;            // hw tile (4096/64)
    int tx = threadIdx.x & 63, ty0 = threadIdx.x >> 6;
#pragma unroll
    for (int k = 0; k < 16; ++k) {
        int c = k * 4 + ty0;
        tile[c][tx] = __builtin_nontemporal_load(
            &f[(size_t)(bc * 64 + c) * HW + bs * 64 + tx]);          // read-once
    }
    __syncthreads();
#pragma unroll
    for (int k = 0; k < 16; ++k) {
        int s = k * 4 + ty0;
        ft[(size_t)(bs * 64 + s) * CC + bc * 64 + tx] = tile[tx][s]; // cached: pool re-reads
    }
}

// ---------- fully-specialized row phase: all windows compile-time ----------
template <int WL, int HL>
__device__ __forceinline__ void pool_rows(
    const float* __restrict__ fbase,     // ft + c0 + lane
    int y1, int x1,
    float (&acc)[7][7])
{
#pragma unroll
    for (int t = 0; t < HL; ++t) {       // FULL unroll: branch-free DAG
        const float* rowp = fbase + (size_t)(y1 + t) * (WW * CC);
        float v[WL];
#pragma unroll
        for (int k = 0; k < WL; ++k)     // exactly WL coalesced loads
            v[k] = rowp[(x1 + k) * CC];
        float m[7];
#pragma unroll
        for (int j = 0; j < 7; ++j) {    // constant w-windows: pure fmax tree
            const int s = (j * WL) / 7;
            const int e = ((j + 1) * WL + 6) / 7;
            float a = v[s];
#pragma unroll
            for (int k = s + 1; k < e; ++k) a = fmaxf(a, v[k]);
            m[j] = a;
        }
#pragma unroll
        for (int i = 0; i < 7; ++i) {    // constant h-windows: folds away
            if (t >= (i * HL) / 7 && t < ((i + 1) * HL + 6) / 7) {
#pragma unroll
                for (int j = 0; j < 7; ++j)
                    acc[i][j] = fmaxf(acc[i][j], m[j]);
            }
        }
    }
}

// ---------- phase 2: persistent pool, per-XCD work-stealing ----------
__global__ __launch_bounds__(256) void pool_kernel(
    const float* __restrict__ ft,        // [H][W][C]
    const int4*  __restrict__ rois,      // [R] (x1,y1,x2,y2) image px
    float* __restrict__ out,             // [R,C,7,7]
    unsigned int* __restrict__ cnt,      // 8 counters, 128B apart (zeroed)
    int nunits)                          // units per XCD == R (one per ROI)
{
    __shared__ __align__(16) float lds[4][32 * 49];
    int wslot = threadIdx.x >> 6;
    int lane  = threadIdx.x & 63;
    int bc = __builtin_amdgcn_readfirstlane(blockIdx.x) & 7;  // XCD key
    int c0 = bc << 6;                    // this XCD's 64-channel chunk
    float* L = lds[wslot];
    unsigned int* my_cnt = &cnt[bc * CNT_STRIDE];   // own 128B line

    for (;;) {
        // wave steals one ROI unit (lane 0 atomic, broadcast to SGPR)
        unsigned int t0 = 0;
        if (lane == 0) t0 = atomicAdd(my_cnt, 1u);
        int r = __builtin_amdgcn_readfirstlane((int)t0);
        if (r >= nunits) break;

        int4 roi = rois[r];              // uniform -> s_load
        // (px * 1/16.f) truncated == px >> 4 for px in [0,1024): exact fp32.
        int x1 = roi.x >> 4, y1 = roi.y >> 4, x2 = roi.z >> 4, y2 = roi.w >> 4;
        int hl = y2 - y1 + 1, wl = x2 - x1 + 1;   // 2..9 each
        wl = min(max(wl, 2), 9);         // safety clamp (construction: [2,9])
        hl = min(max(hl, 2), 9);

        float acc[7][7];
#pragma unroll
        for (int i = 0; i < 7; ++i)
#pragma unroll
            for (int j = 0; j < 7; ++j) acc[i][j] = NEG;

        const float* fbase = ft + c0 + lane;
#define POOL_CASE(W, H) \
        case ((W - 2) * 8 + (H - 2)): pool_rows<W, H>(fbase, y1, x1, acc); break;
#define POOL_CASES_W(W) \
        POOL_CASE(W, 2) POOL_CASE(W, 3) POOL_CASE(W, 4) POOL_CASE(W, 5) \
        POOL_CASE(W, 6) POOL_CASE(W, 7) POOL_CASE(W, 8) POOL_CASE(W, 9)
        switch ((wl - 2) * 8 + (hl - 2)) {   // wave-uniform dispatch
            POOL_CASES_W(2) POOL_CASES_W(3) POOL_CASES_W(4) POOL_CASES_W(5)
            POOL_CASES_W(6) POOL_CASES_W(7) POOL_CASES_W(8) POOL_CASES_W(9)
            default: break;                  // unreachable
        }
#undef POOL_CASES_W
#undef POOL_CASE

        // Store: transpose [64ch][49] -> [c][bin] via LDS, 2 rounds of 32ch.
        float* ob = out + ((size_t)r * CC + c0) * 49;
#pragma unroll
        for (int round = 0; round < 2; ++round) {
            if ((lane >> 5) == round) {
                float* p = L + (lane & 31) * 49;  // stride 49: conflict-free
#pragma unroll
                for (int i = 0; i < 7; ++i)
#pragma unroll
                    for (int j = 0; j < 7; ++j) p[i * 7 + j] = acc[i][j];
            }
            asm volatile("s_waitcnt lgkmcnt(0)" ::: "memory");
            float* og = ob + round * 1568;        // 1568 floats contiguous
#pragma unroll
            for (int s = 0; s < 6; ++s) {         // 6 x (64 lanes x dwordx4)
                int idx = s * 64 + lane;
                __builtin_nontemporal_store(*(const f4*)(L + idx * 4),
                                            (f4*)(og + idx * 4));
            }
            if (lane < 8) {                       // 392 = 6*64 + 8 tail
                int idx = 384 + lane;
                __builtin_nontemporal_store(*(const f4*)(L + idx * 4),
                                            (f4*)(og + idx * 4));
            }
            // LDS reads done before re-deposit (next round / next unit)
            asm volatile("s_waitcnt lgkmcnt(0)" ::: "memory");
        }
    }
}

// ---------- fallback (R4, proven): used only if ws too small ----------
__global__ __launch_bounds__(256) void roi_pool_direct(
    const float* __restrict__ features, const int4* __restrict__ rois,
    float* __restrict__ out, int ngroups)
{
    int wid = __builtin_amdgcn_readfirstlane(
        blockIdx.x * (blockDim.x >> 6) + (threadIdx.x >> 6));
    if (wid >= ngroups) return;
    int lane = threadIdx.x & 63;
    if (lane >= 49) return;
    int r = wid >> 4, c0 = (wid & 15) * 32;
    int4 roi = rois[r];
    int x1 = roi.x >> 4, y1 = roi.y >> 4, x2 = roi.z >> 4, y2 = roi.w >> 4;
    int h_len = y2 - y1 + 1, w_len = x2 - x1 + 1;
    int oh = lane / 7, ow = lane - oh * 7;
    int hs = y1 + (oh * h_len) / 7, he = y1 + ((oh + 1) * h_len + 6) / 7;
    int ws = x1 + (ow * w_len) / 7, we = x1 + ((ow + 1) * w_len + 6) / 7;
    int wlst = we - 1;
    int wa = ws, wb = min(ws + 1, wlst), wc = min(ws + 2, wlst);
    bool need1 = hs + 1 < he, need2 = hs + 2 < he;
    int o0 = (hs * WW + wa) * 4, o0b = (hs * WW + wb) * 4, o0c = (hs * WW + wc) * 4;
    const char* fb = (const char*)features + (size_t)c0 * (HW * 4);
    float* ob = out + ((size_t)r * CC + c0) * 49 + lane;
#pragma unroll 4
    for (int j = 0; j < 32; ++j) {
        float a = fmaxf(fmaxf(*(const float*)(fb + o0),
                              *(const float*)(fb + o0b)),
                        *(const float*)(fb + o0c));
        if (need1) {
            a = fmaxf(a, fmaxf(fmaxf(*(const float*)(fb + o0 + WW * 4),
                                     *(const float*)(fb + o0b + WW * 4)),
                               *(const float*)(fb + o0c + WW * 4)));
        }
        if (need2) {
            a = fmaxf(a, fmaxf(fmaxf(*(const float*)(fb + o0 + 2 * WW * 4),
                                     *(const float*)(fb + o0b + 2 * WW * 4)),
                               *(const float*)(fb + o0c + 2 * WW * 4)));
        }
        *ob = a;
        fb += HW * 4;
        ob += 49;
    }
}

extern "C" void kernel_launch(void* const* d_in, const int* in_sizes, int n_in,
                              void* d_out, int out_size, void* d_ws, size_t ws_size,
                              hipStream_t stream) {
    const float* features = (const float*)d_in[0];   // [1,512,64,64] fp32
    const int4*  rois     = (const int4*)d_in[1];    // [R,4] int32
    float* out = (float*)d_out;
    int R = out_size / (CC * 49);                    // 1024

    if (ws_size >= FT_BYTES + 8 * CNT_STRIDE * sizeof(unsigned int)) {
        float* ft = (float*)d_ws;                    // [HW][C], 8 MB
        unsigned int* cnt = (unsigned int*)((char*)d_ws + FT_BYTES);
        transpose_kernel<<<512, 256, 0, stream>>>(features, ft);
        hipMemsetAsync(cnt, 0, 8 * CNT_STRIDE * sizeof(unsigned int), stream);
        pool_kernel<<<1024, 256, 0, stream>>>(ft, rois, out, cnt, R);
    } else {
        int ngroups = R * 16;
        roi_pool_direct<<<(ngroups + 3) / 4, 256, 0, stream>>>(features, rois, out, ngroups);
    }
}

// Round 17
// 29.491 us; speedup vs baseline: 5.2122x; 1.4306x over previous
//
#include <hip/hip_runtime.h>
#include <float.h>

// ROI adaptive max-pool 7x7. features [512,64,64] fp32, 1024 ROIs.
// == R14 champion with ONE delta: pool blocks are 1 WAVE (64 threads),
// grid 8192 (was 4-wave blocks, grid 2048). Work mapping identical:
// block b -> XCD key bc=b&7, ROI r=b>>3, channels [64bc, 64bc+64).
// Rationale: the HW dispatcher backfills CUs as blocks RETIRE; 1-wave
// blocks retire independently (~16-20 resident/CU), so straggler ROIs
// (duration varies ~20x) are absorbed by dispatcher-level backfill --
// dynamic balancing WITHOUT atomics (R15/R16's explicit work-stealing
// paid more in atomic latency than it won). Wave-inner code is
// byte-identical to R14: templated WL/HL branch-free row DAG, local-XCD
// L2 ft reads, LDS-transpose epilogue, non-temporal stores.
constexpr int CC = 512, HH = 64, WW = 64, HW = HH * WW;
#define NEG (-FLT_MAX)
typedef float f4 __attribute__((ext_vector_type(4)));

// ---------- phase 1: [C][HW] -> [HW][C], XCD-keyed by channel chunk ----------
__global__ __launch_bounds__(256) void transpose_kernel(
    const float* __restrict__ f, float* __restrict__ ft)
{
    __shared__ float tile[64][65];
    int bc = blockIdx.x & 7;             // channel slice -> XCD bc
    int bs = blockIdx.x >> 3;            // hw tile (4096/64)
    int tx = threadIdx.x & 63, ty0 = threadIdx.x >> 6;
#pragma unroll
    for (int k = 0; k < 16; ++k) {
        int c = k * 4 + ty0;
        tile[c][tx] = __builtin_nontemporal_load(
            &f[(size_t)(bc * 64 + c) * HW + bs * 64 + tx]);          // read-once
    }
    __syncthreads();
#pragma unroll
    for (int k = 0; k < 16; ++k) {
        int s = k * 4 + ty0;
        ft[(size_t)(bs * 64 + s) * CC + bc * 64 + tx] = tile[tx][s]; // cached: pool re-reads
    }
}

// ---------- fully-specialized row phase: all windows compile-time ----------
template <int WL, int HL>
__device__ __forceinline__ void pool_rows(
    const float* __restrict__ fbase,     // ft + c0 + lane
    int y1, int x1,
    float (&acc)[7][7])
{
#pragma unroll
    for (int t = 0; t < HL; ++t) {       // FULL unroll: branch-free DAG
        const float* rowp = fbase + (size_t)(y1 + t) * (WW * CC);
        float v[WL];
#pragma unroll
        for (int k = 0; k < WL; ++k)     // exactly WL coalesced loads
            v[k] = rowp[(x1 + k) * CC];
        float m[7];
#pragma unroll
        for (int j = 0; j < 7; ++j) {    // constant w-windows: pure fmax tree
            const int s = (j * WL) / 7;
            const int e = ((j + 1) * WL + 6) / 7;
            float a = v[s];
#pragma unroll
            for (int k = s + 1; k < e; ++k) a = fmaxf(a, v[k]);
            m[j] = a;
        }
#pragma unroll
        for (int i = 0; i < 7; ++i) {    // constant h-windows: folds away
            if (t >= (i * HL) / 7 && t < ((i + 1) * HL + 6) / 7) {
#pragma unroll
                for (int j = 0; j < 7; ++j)
                    acc[i][j] = fmaxf(acc[i][j], m[j]);
            }
        }
    }
}

// ---------- phase 2: pool, 1-wave blocks for dispatcher backfill ----------
__global__ __launch_bounds__(64) void pool_kernel(
    const float* __restrict__ ft,        // [H][W][C]
    const int4*  __restrict__ rois,      // [R] (x1,y1,x2,y2) image px
    float* __restrict__ out,             // [R,C,7,7]
    int nblocks)
{
    __shared__ __align__(16) float lds[32 * 49];
    int b = __builtin_amdgcn_readfirstlane(blockIdx.x);
    if (b >= nblocks) return;
    int lane = threadIdx.x & 63;

    int bc = b & 7;                      // channel chunk == this XCD
    int r  = b >> 3;                     // this wave's ROI
    int c0 = bc << 6;                    // 64-channel chunk base

    int4 roi = rois[r];                  // uniform -> s_load
    // (px * 1/16.f) truncated == px >> 4 for px in [0,1024): exact in fp32.
    int x1 = roi.x >> 4, y1 = roi.y >> 4, x2 = roi.z >> 4, y2 = roi.w >> 4;
    int hl = y2 - y1 + 1, wl = x2 - x1 + 1;   // 2..9 each (16<=bw,bh<128)
    wl = min(max(wl, 2), 9);             // safety clamp (construction: [2,9])
    hl = min(max(hl, 2), 9);

    float acc[7][7];
#pragma unroll
    for (int i = 0; i < 7; ++i)
#pragma unroll
        for (int j = 0; j < 7; ++j) acc[i][j] = NEG;

    const float* fbase = ft + c0 + lane;
#define POOL_CASE(W, H) \
    case ((W - 2) * 8 + (H - 2)): pool_rows<W, H>(fbase, y1, x1, acc); break;
#define POOL_CASES_W(W) \
    POOL_CASE(W, 2) POOL_CASE(W, 3) POOL_CASE(W, 4) POOL_CASE(W, 5) \
    POOL_CASE(W, 6) POOL_CASE(W, 7) POOL_CASE(W, 8) POOL_CASE(W, 9)
    switch ((wl - 2) * 8 + (hl - 2)) {   // wave-uniform dispatch
        POOL_CASES_W(2) POOL_CASES_W(3) POOL_CASES_W(4) POOL_CASES_W(5)
        POOL_CASES_W(6) POOL_CASES_W(7) POOL_CASES_W(8) POOL_CASES_W(9)
        default: break;                  // unreachable
    }
#undef POOL_CASES_W
#undef POOL_CASE

    // Store: transpose [64ch][49] -> flat [c][bin] via LDS, 2 rounds of 32ch.
    float* L  = lds;
    float* ob = out + ((size_t)r * CC + c0) * 49;
#pragma unroll
    for (int round = 0; round < 2; ++round) {
        if ((lane >> 5) == round) {
            float* p = L + (lane & 31) * 49;      // stride 49 (odd): conflict-free
#pragma unroll
            for (int i = 0; i < 7; ++i)
#pragma unroll
                for (int j = 0; j < 7; ++j) p[i * 7 + j] = acc[i][j];
        }
        asm volatile("s_waitcnt lgkmcnt(0)" ::: "memory");
        float* og = ob + round * 1568;            // 1568 floats contiguous
#pragma unroll
        for (int s = 0; s < 6; ++s) {             // 6 x (64 lanes x dwordx4)
            int idx = s * 64 + lane;
            __builtin_nontemporal_store(*(const f4*)(L + idx * 4),
                                        (f4*)(og + idx * 4));
        }
        if (lane < 8) {                           // 392 = 6*64 + 8 tail
            int idx = 384 + lane;
            __builtin_nontemporal_store(*(const f4*)(L + idx * 4),
                                        (f4*)(og + idx * 4));
        }
        asm volatile("s_waitcnt lgkmcnt(0)" ::: "memory"); // reads done before re-write
    }
}

// ---------- fallback (R4, proven): used only if ws_size < 8 MB ----------
__global__ __launch_bounds__(256) void roi_pool_direct(
    const float* __restrict__ features, const int4* __restrict__ rois,
    float* __restrict__ out, int ngroups)
{
    int wid = __builtin_amdgcn_readfirstlane(
        blockIdx.x * (blockDim.x >> 6) + (threadIdx.x >> 6));
    if (wid >= ngroups) return;
    int lane = threadIdx.x & 63;
    if (lane >= 49) return;
    int r = wid >> 4, c0 = (wid & 15) * 32;
    int4 roi = rois[r];
    int x1 = roi.x >> 4, y1 = roi.y >> 4, x2 = roi.z >> 4, y2 = roi.w >> 4;
    int h_len = y2 - y1 + 1, w_len = x2 - x1 + 1;
    int oh = lane / 7, ow = lane - oh * 7;
    int hs = y1 + (oh * h_len) / 7, he = y1 + ((oh + 1) * h_len + 6) / 7;
    int ws = x1 + (ow * w_len) / 7, we = x1 + ((ow + 1) * w_len + 6) / 7;
    int wlst = we - 1;
    int wa = ws, wb = min(ws + 1, wlst), wc = min(ws + 2, wlst);
    bool need1 = hs + 1 < he, need2 = hs + 2 < he;
    int o0 = (hs * WW + wa) * 4, o0b = (hs * WW + wb) * 4, o0c = (hs * WW + wc) * 4;
    const char* fb = (const char*)features + (size_t)c0 * (HW * 4);
    float* ob = out + ((size_t)r * CC + c0) * 49 + lane;
#pragma unroll 4
    for (int j = 0; j < 32; ++j) {
        float a = fmaxf(fmaxf(*(const float*)(fb + o0),
                              *(const float*)(fb + o0b)),
                        *(const float*)(fb + o0c));
        if (need1) {
            a = fmaxf(a, fmaxf(fmaxf(*(const float*)(fb + o0 + WW * 4),
                                     *(const float*)(fb + o0b + WW * 4)),
                               *(const float*)(fb + o0c + WW * 4)));
        }
        if (need2) {
            a = fmaxf(a, fmaxf(fmaxf(*(const float*)(fb + o0 + 2 * WW * 4),
                                     *(const float*)(fb + o0b + 2 * WW * 4)),
                               *(const float*)(fb + o0c + 2 * WW * 4)));
        }
        *ob = a;
        fb += HW * 4;
        ob += 49;
    }
}

extern "C" void kernel_launch(void* const* d_in, const int* in_sizes, int n_in,
                              void* d_out, int out_size, void* d_ws, size_t ws_size,
                              hipStream_t stream) {
    const float* features = (const float*)d_in[0];   // [1,512,64,64] fp32
    const int4*  rois     = (const int4*)d_in[1];    // [R,4] int32
    float* out = (float*)d_out;
    int R = out_size / (CC * 49);                    // 1024

    if (ws_size >= (size_t)CC * HW * sizeof(float)) {
        float* ft = (float*)d_ws;                    // [HW][C], 8 MB
        transpose_kernel<<<512, 256, 0, stream>>>(features, ft);
        int nblocks = R * 8;                         // 1-wave blocks: r*8 + bc
        pool_kernel<<<nblocks, 64, 0, stream>>>(ft, rois, out, nblocks);
    } else {
        int ngroups = R * 16;
        roi_pool_direct<<<(ngroups + 3) / 4, 256, 0, stream>>>(features, rois, out, ngroups);
    }
}